// Round 2
// baseline (450.128 us; speedup 1.0000x reference)
//
#include <hip/hip_runtime.h>

#define LOG2_T 14
#define NKEYS  88
#define NB     16
#define ROWPAD 92   // dwords per lane-row: 16B-aligned stride (368B), bank-spread (92%32=28)

// One wave (64 threads) per 64 consecutive t-columns of one batch b.
// Exact replication of reference f32 math: spec=expf(mel); hps=((s1*s2)*s3)
// with harmonic h active iff bin < ceil(128/h). Multiplying by 1.0f is exact,
// so the branch-free select form is bit-identical to the branchy form.
// probs[k] = (count_j(E_j > E_k) <= 13)  ==  (E_k >= v[74])  ==  (E_k >= thresh),
// since thresh = v[73] + 0.95*(v[74]-v[73]) always lands in (v[73], v[74]].
__global__ __launch_bounds__(64) void tsp_kernel(
    const float* __restrict__ mel,
    const int*   __restrict__ key_bins,
    float*       __restrict__ out)
{
    __shared__ float e_lds[64 * ROWPAD];   // lane-private rows: no barriers needed

    const int lane = threadIdx.x;          // 0..63
    const int bid  = blockIdx.x;           // 4096 blocks
    const int b    = bid >> 8;
    const int t    = ((bid & 255) << 6) + lane;

    const float* melb = mel + ((size_t)b << 21);   // b * 128 * 16384
    float* row = &e_lds[lane * ROWPAD];

    // ---- Phase 1: 88 energies, branch-free, 4 keys per b128 LDS write ----
    #pragma unroll
    for (int k4 = 0; k4 < NKEYS; k4 += 4) {
        float v[4];
        #pragma unroll
        for (int i = 0; i < 4; ++i) {
            const int k   = k4 + i;
            const int bin = key_bins[k];                  // uniform -> s_load
            const int b1  = (2 * bin < 128) ? 2 * bin : 127;
            const int b2  = (3 * bin < 128) ? 3 * bin : 127;
            const float x0 = melb[((size_t)bin << LOG2_T) + t];
            const float x1 = melb[((size_t)b1  << LOG2_T) + t];
            const float x2 = melb[((size_t)b2  << LOG2_T) + t];
            float e = expf(x0);
            e *= (bin < 64) ? expf(x1) : 1.0f;   // harmonic 2: L = 64
            e *= (bin < 43) ? expf(x2) : 1.0f;   // harmonic 3: L = 43
            v[i] = e;
        }
        *reinterpret_cast<float4*>(&row[k4]) =
            make_float4(v[0], v[1], v[2], v[3]);
    }

    // ---- Phase 2: rank counting, 16 register heads x b128 j-stream ----
    float*       out2 = out + ((size_t)(NB * NKEYS) << LOG2_T);  // tuple copy #2
    const size_t col  = (((size_t)b * NKEYS) << LOG2_T) + t;

    for (int c = 0; c < NKEYS; c += 16) {
        float h[16];
        int   cnt[16];
        #pragma unroll
        for (int i = 0; i < 16; ++i) {
            int kk = c + i; if (kk > NKEYS - 1) kk = NKEYS - 1;  // clamp; stores guarded
            h[i]   = row[kk];
            cnt[i] = 0;
        }
        #pragma unroll 2
        for (int j = 0; j < NKEYS; j += 4) {
            const float4 ev = *reinterpret_cast<const float4*>(&row[j]);
            #pragma unroll
            for (int i = 0; i < 16; ++i) {
                cnt[i] += (ev.x > h[i]) ? 1 : 0;
                cnt[i] += (ev.y > h[i]) ? 1 : 0;
                cnt[i] += (ev.z > h[i]) ? 1 : 0;
                cnt[i] += (ev.w > h[i]) ? 1 : 0;
            }
        }
        #pragma unroll
        for (int i = 0; i < 16; ++i) {
            if (c + i < NKEYS) {
                const float  p   = (cnt[i] <= 13) ? 1.0f : 0.0f;
                const size_t idx = col + ((size_t)(c + i) << LOG2_T);
                out[idx]  = p;
                out2[idx] = p;
            }
        }
    }
}

extern "C" void kernel_launch(void* const* d_in, const int* in_sizes, int n_in,
                              void* d_out, int out_size, void* d_ws, size_t ws_size,
                              hipStream_t stream) {
    const float* mel = (const float*)d_in[0];
    const int*   kb  = (const int*)d_in[1];
    float*       out = (float*)d_out;
    tsp_kernel<<<dim3(4096), dim3(64), 0, stream>>>(mel, kb, out);
}

// Round 4
// 302.103 us; speedup vs baseline: 1.4900x; 1.4900x over previous
//
#include <hip/hip_runtime.h>

#define LOG2_T 14
#define NKEYS  88
#define NB     16
#define DMAX   64   // distinct key_bins values (actual ~57); capped, runs partition [0,88)
#define TOPK   14   // #elements >= v[74] in an 88-element ascending sort

// Exact semantics (validated absmax=0 in rounds 1-2):
//   E_d = ((expf(x0) * sel(expf(x1))) * sel(expf(x2)))  — reference f32 order
//   probs = (E >= v74), v74 = weighted 14th-largest (thresh in (v73, v74] always)
// This version: distinct-bin compression + register-resident top-14 extraction.
__global__ __launch_bounds__(256) void tsp_kernel(
    const float* __restrict__ mel,
    const int*   __restrict__ key_bins,
    float*       __restrict__ out)
{
    __shared__ int s_bin[DMAX];    // distinct bin value
    __shared__ int s_mult[DMAX];   // run length (multiplicity)
    __shared__ int s_start[DMAX];  // first key index of run
    __shared__ int s_Dsh;

    if (threadIdx.x == 0) {
        int D = 0, prev = -1;
        for (int k = 0; k < NKEYS; ++k) {
            int bin = key_bins[k];
            if (bin != prev && D < DMAX) {
                s_bin[D] = bin; s_mult[D] = 0; s_start[D] = k; prev = bin; ++D;
            }
            s_mult[D - 1] += 1;
        }
        for (int d = D; d < DMAX; ++d) { s_bin[d] = 0; s_mult[d] = 0; s_start[d] = NKEYS; }
        s_Dsh = D;
    }
    __syncthreads();

    const int tid = threadIdx.x;
    const int bid = blockIdx.x;              // 1024 = 16 batches x 64 column-tiles
    const int b   = bid >> 6;
    const int t   = ((bid & 63) << 8) + tid; // this thread's column
    const int D   = s_Dsh;

    const float* melb = mel + ((size_t)b << 21);   // b * 128 * 16384

    // ---- Phase 1: distinct energies into registers (static-indexed) ----
    float e[DMAX];
    #pragma unroll
    for (int d = 0; d < DMAX; ++d) {
        const int bin = __builtin_amdgcn_readfirstlane(s_bin[d]);
        const int b1  = (2 * bin < 128) ? 2 * bin : 127;   // clamped (load always valid)
        const int b2  = (3 * bin < 128) ? 3 * bin : 127;
        const float x0 = melb[((size_t)bin << LOG2_T) + t];
        const float x1 = melb[((size_t)b1  << LOG2_T) + t];
        const float x2 = melb[((size_t)b2  << LOG2_T) + t];
        float v = expf(x0);
        v *= (bin < 64) ? expf(x1) : 1.0f;   // harmonic 2 active iff bin < 64
        v *= (bin < 43) ? expf(x2) : 1.0f;   // harmonic 3 active iff bin < 43
        e[d] = (d < D) ? v : 0.0f;           // pads: 0 < every real energy, weight 0
    }

    // ---- Phase A: top-14 distinct values, descending (strict max-below scan) ----
    float tv[TOPK];
    float cur = 1e38f;                        // above all energies (|mel| small)
    #pragma unroll
    for (int i = 0; i < TOPK; ++i) {
        float m = -1.0f;
        #pragma unroll
        for (int d = 0; d < DMAX; ++d) {
            const float c = (e[d] < cur) ? e[d] : -1.0f;
            m = fmaxf(m, c);
        }
        tv[i] = m;
        cur = m;
    }

    // ---- Phase B: weighted rank of each candidate in one pass over d ----
    int W[TOPK];
    #pragma unroll
    for (int i = 0; i < TOPK; ++i) W[i] = 0;
    #pragma unroll
    for (int d = 0; d < DMAX; ++d) {
        const int mlt = s_mult[d];            // LDS broadcast, once per d
        const float ed = e[d];
        #pragma unroll
        for (int i = 0; i < TOPK; ++i)
            W[i] += (ed >= tv[i]) ? mlt : 0;
    }
    // v74 = largest candidate with weighted count >= 14
    float thr = tv[TOPK - 1];                 // guaranteed W >= 14 here
    #pragma unroll
    for (int i = TOPK - 2; i >= 0; --i)
        thr = (W[i] >= TOPK) ? tv[i] : thr;

    // ---- Output: per distinct run, broadcast p to its key rows (x2 copies) ----
    float*       out2    = out + ((size_t)(NB * NKEYS) << LOG2_T);
    const size_t colbase = (((size_t)b * NKEYS) << LOG2_T) + t;
    #pragma unroll
    for (int d = 0; d < DMAX; ++d) {
        const int ks = __builtin_amdgcn_readfirstlane(s_start[d]);
        const int ke = __builtin_amdgcn_readfirstlane(s_start[d] + s_mult[d]);
        const float p = (e[d] >= thr) ? 1.0f : 0.0f;
        for (int k = ks; k < ke; ++k) {       // uniform bounds -> no divergence
            const size_t idx = colbase + ((size_t)k << LOG2_T);
            out[idx]  = p;
            out2[idx] = p;
        }
    }
}

extern "C" void kernel_launch(void* const* d_in, const int* in_sizes, int n_in,
                              void* d_out, int out_size, void* d_ws, size_t ws_size,
                              hipStream_t stream) {
    const float* mel = (const float*)d_in[0];
    const int*   kb  = (const int*)d_in[1];
    float*       out = (float*)d_out;
    tsp_kernel<<<dim3(1024), dim3(256), 0, stream>>>(mel, kb, out);
}